// Round 5
// baseline (322.718 us; speedup 1.0000x reference)
//
#include <hip/hip_runtime.h>

// Tensor-product nonlinearity, B=512, MUL=64, l in {0,1,2}.
// out0: (512, 3*4096, 1), out1: (512, 4*4096, 3), out2: (512, 4*4096, 5)
// flat-concatenated in d_out in that order.
//
// Round-6 design (J=4 compute + wave-private LDS transpose + EXPLICIT
// wave-local LDS fences, zero barriers):
//  - each thread owns 4 consecutive c = i*64+j (same i); a-side
//    precontraction wa[n][M] = sum_m w[m][n][M]*a[m] amortized over 4 j's.
//  - out1/out2 stride-3/5 -> lane-contiguous transpose done per-wave in a
//    private 8 KiB LDS region (4 waves x 8 KiB = 32 KiB/block).
//  - Round-3 lesson: the flush ds_read depends on OTHER lanes' ds_writes.
//    That cross-lane dependence is invisible to thread-local alias
//    analysis, so without a fence the scheduler may reorder DS ops across
//    the stage->flush boundary / skip the lgkmcnt wait  -> corrupt out1
//    (absmax 6.6). __syncthreads() previously masked this but force-drains
//    vmcnt(0), serializing all global stores 8x per block (~80us residual).
//  - Fix: asm "s_waitcnt lgkmcnt(0)" + sched_barrier(0) at the two hazard
//    points per round (write->read RAW, read->next-write WAR). vmcnt is
//    untouched -> global stores remain fire-and-forget streaming.
//  - Bank math: stage ds_write_b128 at 12/20-dword lane stride spreads
//    over all bank quads (12,20 coprime-ish mod 32); flush reads are
//    lane-contiguous b128. No conflicts expected.
//  - out0 (D3=1) written direct: already lane-contiguous float4.

#define OUT1_BASE (512 * 12288)               // 6291456
#define OUT2_BASE (OUT1_BASE + 512 * 49152)   // 31457280

// Wave-local LDS fence: all prior DS ops complete & visible, and no memory
// op may be moved across by the compiler. Does NOT drain vmcnt.
#define LDS_FENCE() do {                                  \
    asm volatile("s_waitcnt lgkmcnt(0)" ::: "memory");    \
    __builtin_amdgcn_sched_barrier(0);                    \
} while (0)

// One path (l1,l2,l3), dims D1=2l1+1 etc. w: (D1,D2,D3) row-major.
// a: D1 floats (i-side). bv: 4 j's, bv[jj*D2+n]. o[jj*D3+M].
// Register-only; no LDS access inside.
template<int D1, int D2, int D3>
__device__ __forceinline__ void path_compute(const float* __restrict__ w,
                                             const float* a, const float* bv,
                                             float* o)
{
    float wa[D2 * D3];
#pragma unroll
    for (int k = 0; k < D2 * D3; ++k) wa[k] = 0.f;
#pragma unroll
    for (int m = 0; m < D1; ++m) {
        const float am = a[m];
#pragma unroll
        for (int n = 0; n < D2; ++n)
#pragma unroll
            for (int M = 0; M < D3; ++M)
                wa[n * D3 + M] += w[(m * D2 + n) * D3 + M] * am;
    }
#pragma unroll
    for (int k = 0; k < 4 * D3; ++k) o[k] = 0.f;
#pragma unroll
    for (int jj = 0; jj < 4; ++jj)
#pragma unroll
        for (int n = 0; n < D2; ++n) {
            const float bb = bv[jj * D2 + n];
#pragma unroll
            for (int M = 0; M < D3; ++M)
                o[jj * D3 + M] += wa[n * D3 + M] * bb;
        }
}

// stage this thread's 4c slice into the wave region (M-fast order)
#define STAGE3(optr) do {                                          \
    _Pragma("unroll")                                              \
    for (int q = 0; q < 3; ++q) {                                  \
        float4 v;                                                  \
        v.x = (optr)[4*q+0]; v.y = (optr)[4*q+1];                  \
        v.z = (optr)[4*q+2]; v.w = (optr)[4*q+3];                  \
        *(float4*)(sw + ln * 12 + 4 * q) = v;                      \
    }                                                              \
} while (0)

#define STAGE5(optr) do {                                          \
    _Pragma("unroll")                                              \
    for (int q = 0; q < 5; ++q) {                                  \
        float4 v;                                                  \
        v.x = (optr)[4*q+0]; v.y = (optr)[4*q+1];                  \
        v.z = (optr)[4*q+2]; v.w = (optr)[4*q+3];                  \
        *(float4*)(sw + 768 + ln * 20 + 4 * q) = v;                \
    }                                                              \
} while (0)

// lane-contiguous readback + coalesced global store of the wave slice
#define FLUSH_ROUND(r) do {                                        \
    _Pragma("unroll")                                              \
    for (int q = 0; q < 3; ++q) {                                  \
        const int fo = 4 * (ln + 64 * q);                          \
        float4 v = *(const float4*)(sw + fo);                      \
        *(float4*)(out + o1base + (r) * 12288 + fo) = v;           \
    }                                                              \
    _Pragma("unroll")                                              \
    for (int q = 0; q < 5; ++q) {                                  \
        const int fo = 4 * (ln + 64 * q);                          \
        float4 v = *(const float4*)(sw + 768 + fo);                \
        *(float4*)(out + o2base + (r) * 20480 + fo) = v;           \
    }                                                              \
} while (0)

__global__ __launch_bounds__(256) void tp_kernel(
    const float* __restrict__ x0, const float* __restrict__ x1, const float* __restrict__ x2,
    const float* __restrict__ w000, const float* __restrict__ w011, const float* __restrict__ w022,
    const float* __restrict__ w110, const float* __restrict__ w111, const float* __restrict__ w112,
    const float* __restrict__ w121, const float* __restrict__ w122,
    const float* __restrict__ w220, const float* __restrict__ w221, const float* __restrict__ w222,
    float* out)
{
    // 4 wave-private regions of 2048 dwords: [0,768) out1, [768,2048) out2
    __shared__ __align__(16) float s_out[8192];   // 32 KiB

    const int b   = blockIdx.x >> 2;        // 0..511
    const int seg = blockIdx.x & 3;         // 0..3
    const int t   = threadIdx.x;            // 0..255
    const int wv  = t >> 6;                 // wave id 0..3
    const int ln  = t & 63;                 // lane id
    const int c0  = seg * 1024 + t * 4;     // first of 4 consecutive c
    const int i   = c0 >> 6;                // same for all 4 c
    const int j0  = c0 & 63;                // multiple of 4

    float* sw = s_out + wv * 2048;          // wave-private 8 KiB (no restrict)

    // ---- a-side (i): shared by the thread's 4 outputs ----
    const float a0[1] = { x0[b * 64 + i] };
    float a1[3], a2[5];
#pragma unroll
    for (int m = 0; m < 3; ++m) a1[m] = x1[b * 192 + i * 3 + m];
#pragma unroll
    for (int m = 0; m < 5; ++m) a2[m] = x2[b * 320 + i * 5 + m];

    // ---- b-side (j0..j0+3): vectorized, all 16B-aligned ----
    float b0v[4], b1v[12], b2v[20];
    {
        const float4 v = *(const float4*)(x0 + b * 64 + j0);
        b0v[0] = v.x; b0v[1] = v.y; b0v[2] = v.z; b0v[3] = v.w;
    }
#pragma unroll
    for (int k = 0; k < 3; ++k) {
        const float4 v = *(const float4*)(x1 + b * 192 + j0 * 3 + 4 * k);
        b1v[4 * k + 0] = v.x; b1v[4 * k + 1] = v.y;
        b1v[4 * k + 2] = v.z; b1v[4 * k + 3] = v.w;
    }
#pragma unroll
    for (int k = 0; k < 5; ++k) {
        const float4 v = *(const float4*)(x2 + b * 320 + j0 * 5 + 4 * k);
        b2v[4 * k + 0] = v.x; b2v[4 * k + 1] = v.y;
        b2v[4 * k + 2] = v.z; b2v[4 * k + 3] = v.w;
    }

    float* o0 = out + b * 12288;
    // wave-slice flush bases (dwords): this wave's 256-c slice
    const int o1base = OUT1_BASE + b * 49152 + seg * 3072 + wv * 768;
    const int o2base = OUT2_BASE + b * 81920 + seg * 5120 + wv * 1280;

    float o[20], oo[4];

    // ===== round 0: direct (0,0,0); stage (0,1,1)+(0,2,2); flush =========
#pragma unroll
    for (int jj = 0; jj < 4; ++jj) oo[jj] = w000[0] * (a0[0] * b0v[jj]);
    {
        float4 v; v.x = oo[0]; v.y = oo[1]; v.z = oo[2]; v.w = oo[3];
        *(float4*)(o0 + c0) = v;
    }
    path_compute<1, 3, 3>(w011, a0, b1v, o);  STAGE3(o);
    path_compute<1, 5, 5>(w022, a0, b2v, o);  STAGE5(o);
    LDS_FENCE();               // RAW: other lanes' writes visible
    FLUSH_ROUND(0);
    LDS_FENCE();               // WAR: reads landed before next writes

    // ===== round 1: direct (1,1,0); stage (1,1,1)+(1,1,2); flush =========
    path_compute<3, 3, 1>(w110, a1, b1v, oo);
    {
        float4 v; v.x = oo[0]; v.y = oo[1]; v.z = oo[2]; v.w = oo[3];
        *(float4*)(o0 + 4096 + c0) = v;
    }
    path_compute<3, 3, 3>(w111, a1, b1v, o);  STAGE3(o);
    path_compute<3, 3, 5>(w112, a1, b1v, o);  STAGE5(o);
    LDS_FENCE();
    FLUSH_ROUND(1);
    LDS_FENCE();

    // ===== round 2: stage (1,2,1)+(1,2,2); flush =========================
    path_compute<3, 5, 3>(w121, a1, b2v, o);  STAGE3(o);
    path_compute<3, 5, 5>(w122, a1, b2v, o);  STAGE5(o);
    LDS_FENCE();
    FLUSH_ROUND(2);
    LDS_FENCE();

    // ===== round 3: direct (2,2,0); stage (2,2,1)+(2,2,2); flush =========
    path_compute<5, 5, 1>(w220, a2, b2v, oo);
    {
        float4 v; v.x = oo[0]; v.y = oo[1]; v.z = oo[2]; v.w = oo[3];
        *(float4*)(o0 + 8192 + c0) = v;
    }
    path_compute<5, 5, 3>(w221, a2, b2v, o);  STAGE3(o);
    path_compute<5, 5, 5>(w222, a2, b2v, o);  STAGE5(o);
    LDS_FENCE();
    FLUSH_ROUND(3);
}

extern "C" void kernel_launch(void* const* d_in, const int* in_sizes, int n_in,
                              void* d_out, int out_size, void* d_ws, size_t ws_size,
                              hipStream_t stream) {
    const float* x0   = (const float*)d_in[0];
    const float* x1   = (const float*)d_in[1];
    const float* x2   = (const float*)d_in[2];
    const float* w000 = (const float*)d_in[3];
    const float* w011 = (const float*)d_in[4];
    const float* w022 = (const float*)d_in[5];
    const float* w110 = (const float*)d_in[6];
    const float* w111 = (const float*)d_in[7];
    const float* w112 = (const float*)d_in[8];
    const float* w121 = (const float*)d_in[9];
    const float* w122 = (const float*)d_in[10];
    const float* w220 = (const float*)d_in[11];
    const float* w221 = (const float*)d_in[12];
    const float* w222 = (const float*)d_in[13];
    float* outp = (float*)d_out;

    // 512 b * 4 segments of 1024 c; 256 threads * 4 c each
    dim3 grid(512 * 4);
    dim3 block(256);
    tp_kernel<<<grid, block, 0, stream>>>(x0, x1, x2,
                                          w000, w011, w022, w110, w111, w112,
                                          w121, w122, w220, w221, w222, outp);
}